// Round 2
// baseline (1585.043 us; speedup 1.0000x reference)
//
#include <hip/hip_runtime.h>

#define N_NODES 100000
#define N_EDGES 1600000
#define D 64
#define H 128

// ---------------------------------------------------------------------------
// K1: agg = x   (eps=0 -> out_agg = sum_neighbors + x; fold x into the init).
// agg lives in d_out (exactly [N, D] fp32).
// ---------------------------------------------------------------------------
__global__ __launch_bounds__(256) void k_init(const float4* __restrict__ x4,
                                              float4* __restrict__ agg4, int n4) {
    int i = blockIdx.x * 256 + threadIdx.x;
    if (i < n4) agg4[i] = x4[i];
}

// ---------------------------------------------------------------------------
// K2: scatter-add  agg[dst] += x[src]  over all edges.
// 16 threads per edge; thread c handles floats [4c, 4c+4) of the 64-wide row.
// Within a 16-lane group the float4 gather is one contiguous 256B row.
// NOTE: harness passes integer inputs as int32 (not the reference's int64).
// ---------------------------------------------------------------------------
__global__ __launch_bounds__(256) void k_scatter(const float4* __restrict__ x4,
                                                 const int* __restrict__ src,
                                                 const int* __restrict__ dst,
                                                 float* __restrict__ agg) {
    int gid = blockIdx.x * 256 + threadIdx.x;
    int e = gid >> 4;
    if (e >= N_EDGES) return;
    int c = gid & 15;
    int s = src[e];
    int d = dst[e];
    float4 v = x4[s * 16 + c];
    float* p = agg + (size_t)d * D + c * 4;
    atomicAdd(p + 0, v.x);
    atomicAdd(p + 1, v.y);
    atomicAdd(p + 2, v.z);
    atomicAdd(p + 3, v.w);
}

// ---------------------------------------------------------------------------
// K3 (fused MLP): out = relu(agg@W1 + b1) @ W2 + b2, in-place on d_out rows.
// 8 nodes per block (256 threads = 8 groups of 32 lanes).
// LDS: one 32KB weight buffer reused for W1 then W2; sh holds the hidden
// activations between stages. Each block reads and writes only its own 8
// rows of d_out, so in-place is race-free.
// Bank behavior: weight reads are lane-stride-1 (conflict-free); sx/sh reads
// are same-address broadcasts within each 32-lane group.
// ---------------------------------------------------------------------------
__global__ __launch_bounds__(256) void k_mlp(float* __restrict__ io,   // d_out: agg in, out out
                                             const float* __restrict__ W1,
                                             const float* __restrict__ b1,
                                             const float* __restrict__ W2,
                                             const float* __restrict__ b2) {
    __shared__ float sW[D * H];      // 32 KB, reused W1 -> W2
    __shared__ float sb1[H];
    __shared__ float sb2[D];
    __shared__ float sx[8][D];       // 2 KB
    __shared__ float sh[8][H];       // 4 KB

    int t = threadIdx.x;
    int base = blockIdx.x * 8;

    // stage W1 + biases + this block's 8 agg rows
    for (int i = t; i < D * H; i += 256) sW[i] = W1[i];
    if (t < H) sb1[t] = b1[t];
    if (t >= H && t < H + D) sb2[t - H] = b2[t - H];
    for (int i = t; i < 8 * D; i += 256) {
        int n = base + (i >> 6);
        sx[i >> 6][i & 63] = (n < N_NODES) ? io[(size_t)n * D + (i & 63)] : 0.f;
    }
    __syncthreads();

    int n = t >> 5;       // node within block (0..7)
    int lane = t & 31;

    // stage 1: h[n][lane + 32k] = relu(sum_i x[n][i] * W1[i][lane+32k] + b1)
    float acc[4];
#pragma unroll
    for (int k = 0; k < 4; k++) acc[k] = sb1[lane + 32 * k];
    for (int i = 0; i < D; i++) {
        float xv = sx[n][i];
#pragma unroll
        for (int k = 0; k < 4; k++) acc[k] += xv * sW[i * H + lane + 32 * k];
    }
#pragma unroll
    for (int k = 0; k < 4; k++) sh[n][lane + 32 * k] = fmaxf(acc[k], 0.f);
    __syncthreads();                 // all W1 reads + sh writes done

    // reload weight buffer with W2 [H, D]
    for (int i = t; i < H * D; i += 256) sW[i] = W2[i];
    __syncthreads();

    // stage 2: out[n][lane + 32m] = sum_j h[n][j] * W2[j][lane+32m] + b2
    float o[2];
#pragma unroll
    for (int m = 0; m < 2; m++) o[m] = sb2[lane + 32 * m];
    for (int j = 0; j < H; j++) {
        float hv = sh[n][j];
#pragma unroll
        for (int m = 0; m < 2; m++) o[m] += hv * sW[j * D + lane + 32 * m];
    }
    int node = base + n;
    if (node < N_NODES) {
#pragma unroll
        for (int m = 0; m < 2; m++)
            io[(size_t)node * D + lane + 32 * m] = o[m];
    }
}

// ---------------------------------------------------------------------------
extern "C" void kernel_launch(void* const* d_in, const int* in_sizes, int n_in,
                              void* d_out, int out_size, void* d_ws, size_t ws_size,
                              hipStream_t stream) {
    const float* x   = (const float*)d_in[0];
    const int* eidx  = (const int*)d_in[1];    // [2, N_EDGES], int32 per harness
    const float* W1  = (const float*)d_in[2];
    const float* b1  = (const float*)d_in[3];
    const float* W2  = (const float*)d_in[4];
    const float* b2  = (const float*)d_in[5];
    float* out       = (float*)d_out;          // used as agg buffer, then out

    const int* src = eidx;
    const int* dst = eidx + N_EDGES;

    // K1: agg = x  (into d_out)
    int n4 = N_NODES * D / 4;
    k_init<<<(n4 + 255) / 256, 256, 0, stream>>>((const float4*)x, (float4*)out, n4);

    // K2: scatter-add over edges (into d_out)
    long long total = (long long)N_EDGES * 16;
    k_scatter<<<(int)((total + 255) / 256), 256, 0, stream>>>(
        (const float4*)x, src, dst, out);

    // K3: fused MLP, in-place on d_out
    int nb = (N_NODES + 7) / 8;                // 12500 blocks
    k_mlp<<<nb, 256, 0, stream>>>(out, W1, b1, W2, b2);
}

// Round 3
// 417.050 us; speedup vs baseline: 3.8006x; 3.8006x over previous
//
#include <hip/hip_runtime.h>

#define N_NODES 100000
#define N_EDGES 1600000
#define D 64
#define H 128
#define SCAN_BS 512
#define SCAN_NBLK ((N_NODES + SCAN_BS - 1) / SCAN_BS)   // 196

// ===========================================================================
// CSR build: zero -> hist -> scan(3 kernels) -> fill
// ===========================================================================
__global__ __launch_bounds__(256) void k_zero(int* __restrict__ p, int n) {
    int i = blockIdx.x * 256 + threadIdx.x;
    if (i < n) p[i] = 0;
}

__global__ __launch_bounds__(256) void k_hist(const int* __restrict__ dst,
                                              int* __restrict__ cnt) {
    int e = blockIdx.x * 256 + threadIdx.x;
    if (e < N_EDGES) atomicAdd(&cnt[dst[e]], 1);
}

// inclusive scan, phase 1: per-block scan of 512 elems + block sums
__global__ __launch_bounds__(SCAN_BS) void k_scan1(const int* __restrict__ cnt,
                                                   int* __restrict__ ends,
                                                   int* __restrict__ bsum) {
    __shared__ int s[SCAN_BS];
    int t = threadIdx.x, b = blockIdx.x;
    int id = b * SCAN_BS + t;
    s[t] = (id < N_NODES) ? cnt[id] : 0;
    __syncthreads();
    for (int off = 1; off < SCAN_BS; off <<= 1) {
        int u = (t >= off) ? s[t - off] : 0;
        __syncthreads();
        s[t] += u;
        __syncthreads();
    }
    if (id < N_NODES) ends[id] = s[t];
    if (t == SCAN_BS - 1) bsum[b] = s[t];
}

// phase 2: scan the 196 block sums in one block (256 threads, padded)
__global__ __launch_bounds__(256) void k_scan2(int* __restrict__ bsum) {
    __shared__ int s[256];
    int t = threadIdx.x;
    s[t] = (t < SCAN_NBLK) ? bsum[t] : 0;
    __syncthreads();
    for (int off = 1; off < 256; off <<= 1) {
        int u = (t >= off) ? s[t - off] : 0;
        __syncthreads();
        s[t] += u;
        __syncthreads();
    }
    if (t < SCAN_NBLK) bsum[t] = s[t];
}

// phase 3: add scanned block sums
__global__ __launch_bounds__(SCAN_BS) void k_scan3(int* __restrict__ ends,
                                                   const int* __restrict__ bsum) {
    int t = threadIdx.x, b = blockIdx.x;
    int id = b * SCAN_BS + t;
    if (b > 0 && id < N_NODES) ends[id] += bsum[b - 1];
}

__global__ __launch_bounds__(256) void k_fill(const int* __restrict__ src,
                                              const int* __restrict__ dst,
                                              const int* __restrict__ ends,
                                              int* __restrict__ cursor,
                                              int* __restrict__ csr) {
    int e = blockIdx.x * 256 + threadIdx.x;
    if (e >= N_EDGES) return;
    int d = dst[e];
    int pos = atomicAdd(&cursor[d], 1);
    int start = (d > 0) ? ends[d - 1] : 0;
    csr[start + pos] = src[e];
}

// ===========================================================================
// Atomic-free aggregation: one 64-lane wave per node, lane = feature.
// out[node][f] = x[node][f] + sum_{e in csr[node]} x[src_e][f]
// Row gathers are 256B coalesced per wave; 4 partial sums for ILP.
// ===========================================================================
__global__ __launch_bounds__(256) void k_agg(const float* __restrict__ x,
                                             const int* __restrict__ csr,
                                             const int* __restrict__ ends,
                                             float* __restrict__ out) {
    int node = blockIdx.x * 4 + (threadIdx.x >> 6);
    if (node >= N_NODES) return;
    int f = threadIdx.x & 63;
    int start = (node > 0) ? ends[node - 1] : 0;
    int end = ends[node];
    float a0 = x[(size_t)node * D + f], a1 = 0.f, a2 = 0.f, a3 = 0.f;
    int e = start;
    for (; e + 4 <= end; e += 4) {
        int s0 = csr[e], s1 = csr[e + 1], s2 = csr[e + 2], s3 = csr[e + 3];
        a0 += x[(size_t)s0 * D + f];
        a1 += x[(size_t)s1 * D + f];
        a2 += x[(size_t)s2 * D + f];
        a3 += x[(size_t)s3 * D + f];
    }
    for (; e < end; e++) a0 += x[(size_t)csr[e] * D + f];
    out[(size_t)node * D + f] = (a0 + a1) + (a2 + a3);
}

// ===========================================================================
// Fallback (ws too small): atomic scatter path (proven in R2)
// ===========================================================================
__global__ __launch_bounds__(256) void k_init(const float4* __restrict__ x4,
                                              float4* __restrict__ agg4, int n4) {
    int i = blockIdx.x * 256 + threadIdx.x;
    if (i < n4) agg4[i] = x4[i];
}

__global__ __launch_bounds__(256) void k_scatter(const float4* __restrict__ x4,
                                                 const int* __restrict__ src,
                                                 const int* __restrict__ dst,
                                                 float* __restrict__ agg) {
    int gid = blockIdx.x * 256 + threadIdx.x;
    int e = gid >> 4;
    if (e >= N_EDGES) return;
    int c = gid & 15;
    float4 v = x4[src[e] * 16 + c];
    float* p = agg + (size_t)dst[e] * D + c * 4;
    atomicAdd(p + 0, v.x);
    atomicAdd(p + 1, v.y);
    atomicAdd(p + 2, v.z);
    atomicAdd(p + 3, v.w);
}

// ===========================================================================
// Fused MLP, in-place on d_out. 32 nodes/block, 4x4 register tiling.
// group g (32 lanes) handles nodes {g, g+8, g+16, g+24}.
// LDS: 32KB weights (reused W1->W2) + 16KB sh + 8KB sx ~= 57KB -> 2 blocks/CU.
// ===========================================================================
__global__ __launch_bounds__(256) void k_mlp(float* __restrict__ io,
                                             const float* __restrict__ W1,
                                             const float* __restrict__ b1,
                                             const float* __restrict__ W2,
                                             const float* __restrict__ b2) {
    __shared__ float sW[D * H];      // 32 KB
    __shared__ float sb1[H];
    __shared__ float sb2[D];
    __shared__ float sx[32][D];      // 8 KB
    __shared__ float sh[32][H];      // 16 KB

    int t = threadIdx.x;
    int base = blockIdx.x * 32;

    for (int i = t; i < D * H; i += 256) sW[i] = W1[i];
    if (t < H) sb1[t] = b1[t];
    if (t >= H && t < H + D) sb2[t - H] = b2[t - H];
    for (int i = t; i < 32 * D; i += 256) {
        int n = base + (i >> 6);
        sx[i >> 6][i & 63] = (n < N_NODES) ? io[(size_t)n * D + (i & 63)] : 0.f;
    }
    __syncthreads();

    int g = t >> 5, lane = t & 31;

    // stage 1: h = relu(x @ W1 + b1), 4 nodes x 4 outputs per thread
    float acc[4][4];
#pragma unroll
    for (int nn = 0; nn < 4; nn++)
#pragma unroll
        for (int k = 0; k < 4; k++) acc[nn][k] = sb1[lane + 32 * k];
    for (int i = 0; i < D; i++) {
        float w0 = sW[i * H + lane], w1 = sW[i * H + lane + 32];
        float w2 = sW[i * H + lane + 64], w3 = sW[i * H + lane + 96];
#pragma unroll
        for (int nn = 0; nn < 4; nn++) {
            float xv = sx[g + 8 * nn][i];
            acc[nn][0] += xv * w0;
            acc[nn][1] += xv * w1;
            acc[nn][2] += xv * w2;
            acc[nn][3] += xv * w3;
        }
    }
#pragma unroll
    for (int nn = 0; nn < 4; nn++)
#pragma unroll
        for (int k = 0; k < 4; k++)
            sh[g + 8 * nn][lane + 32 * k] = fmaxf(acc[nn][k], 0.f);
    __syncthreads();

    for (int i = t; i < H * D; i += 256) sW[i] = W2[i];
    __syncthreads();

    // stage 2: out = h @ W2 + b2, 4 nodes x 2 outputs per thread
    float o[4][2];
#pragma unroll
    for (int nn = 0; nn < 4; nn++) { o[nn][0] = sb2[lane]; o[nn][1] = sb2[lane + 32]; }
    for (int j = 0; j < H; j++) {
        float w0 = sW[j * D + lane], w1 = sW[j * D + lane + 32];
#pragma unroll
        for (int nn = 0; nn < 4; nn++) {
            float hv = sh[g + 8 * nn][j];
            o[nn][0] += hv * w0;
            o[nn][1] += hv * w1;
        }
    }
#pragma unroll
    for (int nn = 0; nn < 4; nn++) {
        int node = base + g + 8 * nn;
        if (node < N_NODES) {
            io[(size_t)node * D + lane]      = o[nn][0];
            io[(size_t)node * D + lane + 32] = o[nn][1];
        }
    }
}

// ===========================================================================
extern "C" void kernel_launch(void* const* d_in, const int* in_sizes, int n_in,
                              void* d_out, int out_size, void* d_ws, size_t ws_size,
                              hipStream_t stream) {
    const float* x  = (const float*)d_in[0];
    const int* eidx = (const int*)d_in[1];   // [2, N_EDGES] int32 per harness
    const float* W1 = (const float*)d_in[2];
    const float* b1 = (const float*)d_in[3];
    const float* W2 = (const float*)d_in[4];
    const float* b2 = (const float*)d_in[5];
    float* out      = (float*)d_out;         // agg buffer, then final output

    const int* src = eidx;
    const int* dst = eidx + N_EDGES;

    // ws layout: cnt[N] ends[N] cursor[N] bsum[512] csr[E]
    size_t need = (size_t)(3 * N_NODES + 512 + N_EDGES) * sizeof(int);  // ~7.6 MB

    if (ws_size >= need) {
        int* cnt    = (int*)d_ws;
        int* ends   = cnt + N_NODES;
        int* cursor = ends + N_NODES;
        int* bsum   = cursor + N_NODES;
        int* csr    = bsum + 512;

        k_zero<<<(2 * N_NODES + 255) / 256, 256, 0, stream>>>(cnt, 2 * N_NODES); // cnt+ends? no: cnt,ends contiguous; cursor zeroed below
        // note: zeroes cnt[N] and ends[N]; ends gets overwritten by scan anyway,
        // cursor needs zeroing too:
        k_zero<<<(N_NODES + 255) / 256, 256, 0, stream>>>(cursor, N_NODES);

        k_hist<<<(N_EDGES + 255) / 256, 256, 0, stream>>>(dst, cnt);
        k_scan1<<<SCAN_NBLK, SCAN_BS, 0, stream>>>(cnt, ends, bsum);
        k_scan2<<<1, 256, 0, stream>>>(bsum);
        k_scan3<<<SCAN_NBLK, SCAN_BS, 0, stream>>>(ends, bsum);
        k_fill<<<(N_EDGES + 255) / 256, 256, 0, stream>>>(src, dst, ends, cursor, csr);
        k_agg<<<(N_NODES + 3) / 4, 256, 0, stream>>>(x, csr, ends, out);
    } else {
        // fallback: proven atomic path
        int n4 = N_NODES * D / 4;
        k_init<<<(n4 + 255) / 256, 256, 0, stream>>>((const float4*)x, (float4*)out, n4);
        long long total = (long long)N_EDGES * 16;
        k_scatter<<<(int)((total + 255) / 256), 256, 0, stream>>>(
            (const float4*)x, src, dst, out);
    }

    k_mlp<<<(N_NODES + 31) / 32, 256, 0, stream>>>(out, W1, b1, W2, b2);
}

// Round 4
// 333.976 us; speedup vs baseline: 4.7460x; 1.2487x over previous
//
#include <hip/hip_runtime.h>

#define N_NODES 100000
#define N_EDGES 1600000
#define D 64
#define H 128
#define SCAN_BS 512
#define SCAN_NBLK ((N_NODES + SCAN_BS - 1) / SCAN_BS)   // 196

// ===========================================================================
// utility
// ===========================================================================
__global__ __launch_bounds__(256) void k_zero(int* __restrict__ p, int n) {
    int i = blockIdx.x * 256 + threadIdx.x;
    if (i < n) p[i] = 0;
}

// ===========================================================================
// hist + per-edge position: pos[e] = old count of dst[e].
// Moves the atomic OFF k_fill's store path; pos write is streaming/coalesced.
// ===========================================================================
__global__ __launch_bounds__(256) void k_histpos(const int* __restrict__ dst,
                                                 int* __restrict__ cnt,
                                                 int* __restrict__ pos) {
    int e = blockIdx.x * 256 + threadIdx.x;
    if (e < N_EDGES) pos[e] = atomicAdd(&cnt[dst[e]], 1);
}

__global__ __launch_bounds__(256) void k_hist(const int* __restrict__ dst,
                                              int* __restrict__ cnt) {
    int e = blockIdx.x * 256 + threadIdx.x;
    if (e < N_EDGES) atomicAdd(&cnt[dst[e]], 1);
}

// ===========================================================================
// inclusive scan of cnt -> ends (3 phases)
// ===========================================================================
__global__ __launch_bounds__(SCAN_BS) void k_scan1(const int* __restrict__ cnt,
                                                   int* __restrict__ ends,
                                                   int* __restrict__ bsum) {
    __shared__ int s[SCAN_BS];
    int t = threadIdx.x, b = blockIdx.x;
    int id = b * SCAN_BS + t;
    s[t] = (id < N_NODES) ? cnt[id] : 0;
    __syncthreads();
    for (int off = 1; off < SCAN_BS; off <<= 1) {
        int u = (t >= off) ? s[t - off] : 0;
        __syncthreads();
        s[t] += u;
        __syncthreads();
    }
    if (id < N_NODES) ends[id] = s[t];
    if (t == SCAN_BS - 1) bsum[b] = s[t];
}

__global__ __launch_bounds__(256) void k_scan2(int* __restrict__ bsum) {
    __shared__ int s[256];
    int t = threadIdx.x;
    s[t] = (t < SCAN_NBLK) ? bsum[t] : 0;
    __syncthreads();
    for (int off = 1; off < 256; off <<= 1) {
        int u = (t >= off) ? s[t - off] : 0;
        __syncthreads();
        s[t] += u;
        __syncthreads();
    }
    if (t < SCAN_NBLK) bsum[t] = s[t];
}

__global__ __launch_bounds__(SCAN_BS) void k_scan3(int* __restrict__ ends,
                                                   const int* __restrict__ bsum) {
    int t = threadIdx.x, b = blockIdx.x;
    int id = b * SCAN_BS + t;
    if (b > 0 && id < N_NODES) ends[id] += bsum[b - 1];
}

// ===========================================================================
// atomic-free CSR fill: coalesced reads + one scattered 4B store.
// ===========================================================================
__global__ __launch_bounds__(256) void k_fill2(const int* __restrict__ src,
                                               const int* __restrict__ dst,
                                               const int* __restrict__ pos,
                                               const int* __restrict__ ends,
                                               int* __restrict__ csr) {
    int e = blockIdx.x * 256 + threadIdx.x;
    if (e >= N_EDGES) return;
    int d = dst[e];
    int start = (d > 0) ? ends[d - 1] : 0;
    csr[start + pos[e]] = src[e];
}

// fallback fill with cursor atomics (R3-proven, smaller ws footprint)
__global__ __launch_bounds__(256) void k_fill(const int* __restrict__ src,
                                              const int* __restrict__ dst,
                                              const int* __restrict__ ends,
                                              int* __restrict__ cursor,
                                              int* __restrict__ csr) {
    int e = blockIdx.x * 256 + threadIdx.x;
    if (e >= N_EDGES) return;
    int d = dst[e];
    int p = atomicAdd(&cursor[d], 1);
    int start = (d > 0) ? ends[d - 1] : 0;
    csr[start + p] = src[e];
}

// ===========================================================================
// Atomic-free aggregation: one 64-lane wave per node, lane = feature.
// ===========================================================================
__global__ __launch_bounds__(256) void k_agg(const float* __restrict__ x,
                                             const int* __restrict__ csr,
                                             const int* __restrict__ ends,
                                             float* __restrict__ out) {
    int node = blockIdx.x * 4 + (threadIdx.x >> 6);
    if (node >= N_NODES) return;
    int f = threadIdx.x & 63;
    int start = (node > 0) ? ends[node - 1] : 0;
    int end = ends[node];
    float a0 = x[(size_t)node * D + f], a1 = 0.f, a2 = 0.f, a3 = 0.f;
    int e = start;
    for (; e + 4 <= end; e += 4) {
        int s0 = csr[e], s1 = csr[e + 1], s2 = csr[e + 2], s3 = csr[e + 3];
        a0 += x[(size_t)s0 * D + f];
        a1 += x[(size_t)s1 * D + f];
        a2 += x[(size_t)s2 * D + f];
        a3 += x[(size_t)s3 * D + f];
    }
    for (; e < end; e++) a0 += x[(size_t)csr[e] * D + f];
    out[(size_t)node * D + f] = (a0 + a1) + (a2 + a3);
}

// ===========================================================================
// last-resort fallback: atomic scatter (R2-proven)
// ===========================================================================
__global__ __launch_bounds__(256) void k_init(const float4* __restrict__ x4,
                                              float4* __restrict__ agg4, int n4) {
    int i = blockIdx.x * 256 + threadIdx.x;
    if (i < n4) agg4[i] = x4[i];
}

__global__ __launch_bounds__(256) void k_scatter(const float4* __restrict__ x4,
                                                 const int* __restrict__ src,
                                                 const int* __restrict__ dst,
                                                 float* __restrict__ agg) {
    int gid = blockIdx.x * 256 + threadIdx.x;
    int e = gid >> 4;
    if (e >= N_EDGES) return;
    int c = gid & 15;
    float4 v = x4[src[e] * 16 + c];
    float* p = agg + (size_t)dst[e] * D + c * 4;
    atomicAdd(p + 0, v.x);
    atomicAdd(p + 1, v.y);
    atomicAdd(p + 2, v.z);
    atomicAdd(p + 3, v.w);
}

// ===========================================================================
// Fused MLP, in-place on d_out. 32 nodes/block, packed-weight LDS layout so
// weight reads are ds_read_b128/b64 (lane-stride 16B/8B = conflict-free;
// the b64 pattern is 2-way which is free) and activation reads are b128
// broadcasts. Stage-1 LDS instrs/thread: 512 (b32) -> 128 (b128).
// ===========================================================================
#define FMA4(acc, xs, w) { acc.x += (xs)*w.x; acc.y += (xs)*w.y; acc.z += (xs)*w.z; acc.w += (xs)*w.w; }
#define FMA2(o, hs, w)   { o.x  += (hs)*w.x;  o.y  += (hs)*w.y; }

__global__ __launch_bounds__(256) void k_mlp(float* __restrict__ io,
                                             const float* __restrict__ W1,
                                             const float* __restrict__ b1,
                                             const float* __restrict__ W2,
                                             const float* __restrict__ b2) {
    __shared__ float sW[D * H];      // 32 KB, packed; reused W1 -> W2
    __shared__ float sb1[H];
    __shared__ float sb2[D];
    __shared__ float sx[32][D];      // 8 KB
    __shared__ float sh[32][H];      // 16 KB

    int t = threadIdx.x;
    int base = blockIdx.x * 32;

    // pack W1: sW[(i*32 + l)*4 + k] = W1[i*H + l + 32k]
    for (int p = t; p < D * H; p += 256) {
        int k = p & 3, l = (p >> 2) & 31, i = p >> 7;
        sW[p] = W1[i * H + l + 32 * k];
    }
    if (t < H) sb1[t] = b1[t];
    if (t >= H && t < H + D) sb2[t - H] = b2[t - H];
    for (int p = t; p < 32 * D; p += 256) {
        int n = base + (p >> 6);
        sx[p >> 6][p & 63] = (n < N_NODES) ? io[(size_t)n * D + (p & 63)] : 0.f;
    }
    __syncthreads();

    int g = t >> 5, lane = t & 31;

    // ---- stage 1: h = relu(x @ W1 + b1); 4 nodes x 4 outputs per thread ----
    float4 acc0 = make_float4(sb1[lane], sb1[lane + 32], sb1[lane + 64], sb1[lane + 96]);
    float4 acc1 = acc0, acc2 = acc0, acc3 = acc0;
    for (int i = 0; i < D; i += 4) {
        float4 x0 = *(const float4*)&sx[g][i];
        float4 x1 = *(const float4*)&sx[g + 8][i];
        float4 x2 = *(const float4*)&sx[g + 16][i];
        float4 x3 = *(const float4*)&sx[g + 24][i];
        float4 w;
        w = *(const float4*)&sW[((i + 0) * 32 + lane) * 4];
        FMA4(acc0, x0.x, w) FMA4(acc1, x1.x, w) FMA4(acc2, x2.x, w) FMA4(acc3, x3.x, w)
        w = *(const float4*)&sW[((i + 1) * 32 + lane) * 4];
        FMA4(acc0, x0.y, w) FMA4(acc1, x1.y, w) FMA4(acc2, x2.y, w) FMA4(acc3, x3.y, w)
        w = *(const float4*)&sW[((i + 2) * 32 + lane) * 4];
        FMA4(acc0, x0.z, w) FMA4(acc1, x1.z, w) FMA4(acc2, x2.z, w) FMA4(acc3, x3.z, w)
        w = *(const float4*)&sW[((i + 3) * 32 + lane) * 4];
        FMA4(acc0, x0.w, w) FMA4(acc1, x1.w, w) FMA4(acc2, x2.w, w) FMA4(acc3, x3.w, w)
    }
    sh[g][lane]           = fmaxf(acc0.x, 0.f);
    sh[g][lane + 32]      = fmaxf(acc0.y, 0.f);
    sh[g][lane + 64]      = fmaxf(acc0.z, 0.f);
    sh[g][lane + 96]      = fmaxf(acc0.w, 0.f);
    sh[g + 8][lane]       = fmaxf(acc1.x, 0.f);
    sh[g + 8][lane + 32]  = fmaxf(acc1.y, 0.f);
    sh[g + 8][lane + 64]  = fmaxf(acc1.z, 0.f);
    sh[g + 8][lane + 96]  = fmaxf(acc1.w, 0.f);
    sh[g + 16][lane]      = fmaxf(acc2.x, 0.f);
    sh[g + 16][lane + 32] = fmaxf(acc2.y, 0.f);
    sh[g + 16][lane + 64] = fmaxf(acc2.z, 0.f);
    sh[g + 16][lane + 96] = fmaxf(acc2.w, 0.f);
    sh[g + 24][lane]      = fmaxf(acc3.x, 0.f);
    sh[g + 24][lane + 32] = fmaxf(acc3.y, 0.f);
    sh[g + 24][lane + 64] = fmaxf(acc3.z, 0.f);
    sh[g + 24][lane + 96] = fmaxf(acc3.w, 0.f);
    __syncthreads();                 // stage-1 sW reads + sh writes complete

    // pack W2: sW[(j*32 + l)*2 + m] = W2[j*D + l + 32m]
    for (int p = t; p < H * D; p += 256) {
        int m = p & 1, l = (p >> 1) & 31, j = p >> 6;
        sW[p] = W2[j * D + l + 32 * m];
    }
    __syncthreads();

    // ---- stage 2: out = h @ W2 + b2; 4 nodes x 2 outputs per thread ----
    float2 o0 = make_float2(sb2[lane], sb2[lane + 32]);
    float2 o1 = o0, o2 = o0, o3 = o0;
    for (int j = 0; j < H; j += 4) {
        float4 h0 = *(const float4*)&sh[g][j];
        float4 h1 = *(const float4*)&sh[g + 8][j];
        float4 h2 = *(const float4*)&sh[g + 16][j];
        float4 h3 = *(const float4*)&sh[g + 24][j];
        float2 w;
        w = *(const float2*)&sW[((j + 0) * 32 + lane) * 2];
        FMA2(o0, h0.x, w) FMA2(o1, h1.x, w) FMA2(o2, h2.x, w) FMA2(o3, h3.x, w)
        w = *(const float2*)&sW[((j + 1) * 32 + lane) * 2];
        FMA2(o0, h0.y, w) FMA2(o1, h1.y, w) FMA2(o2, h2.y, w) FMA2(o3, h3.y, w)
        w = *(const float2*)&sW[((j + 2) * 32 + lane) * 2];
        FMA2(o0, h0.z, w) FMA2(o1, h1.z, w) FMA2(o2, h2.z, w) FMA2(o3, h3.z, w)
        w = *(const float2*)&sW[((j + 3) * 32 + lane) * 2];
        FMA2(o0, h0.w, w) FMA2(o1, h1.w, w) FMA2(o2, h2.w, w) FMA2(o3, h3.w, w)
    }
    int n0 = base + g;
    if (n0 < N_NODES)      { io[(size_t)n0 * D + lane] = o0.x; io[(size_t)n0 * D + lane + 32] = o0.y; }
    int n1 = base + g + 8;
    if (n1 < N_NODES)      { io[(size_t)n1 * D + lane] = o1.x; io[(size_t)n1 * D + lane + 32] = o1.y; }
    int n2 = base + g + 16;
    if (n2 < N_NODES)      { io[(size_t)n2 * D + lane] = o2.x; io[(size_t)n2 * D + lane + 32] = o2.y; }
    int n3 = base + g + 24;
    if (n3 < N_NODES)      { io[(size_t)n3 * D + lane] = o3.x; io[(size_t)n3 * D + lane + 32] = o3.y; }
}

// ===========================================================================
extern "C" void kernel_launch(void* const* d_in, const int* in_sizes, int n_in,
                              void* d_out, int out_size, void* d_ws, size_t ws_size,
                              hipStream_t stream) {
    const float* x  = (const float*)d_in[0];
    const int* eidx = (const int*)d_in[1];   // [2, N_EDGES] int32 per harness
    const float* W1 = (const float*)d_in[2];
    const float* b1 = (const float*)d_in[3];
    const float* W2 = (const float*)d_in[4];
    const float* b2 = (const float*)d_in[5];
    float* out      = (float*)d_out;         // agg buffer, then final output

    const int* src = eidx;
    const int* dst = eidx + N_EDGES;

    // preferred ws layout: cnt[N] ends[N] bsum[512] pos[E] csr[E]  (~13.6 MB)
    size_t need_new = (size_t)(2 * N_NODES + 512 + 2 * N_EDGES) * sizeof(int);
    // fallback layout:     cnt[N] ends[N] cursor[N] bsum[512] csr[E] (~7.6 MB)
    size_t need_old = (size_t)(3 * N_NODES + 512 + N_EDGES) * sizeof(int);

    int ge = (N_EDGES + 255) / 256;

    if (ws_size >= need_new) {
        int* cnt  = (int*)d_ws;
        int* ends = cnt + N_NODES;
        int* bsum = ends + N_NODES;
        int* pos  = bsum + 512;
        int* csr  = pos + N_EDGES;

        k_zero<<<(N_NODES + 255) / 256, 256, 0, stream>>>(cnt, N_NODES);
        k_histpos<<<ge, 256, 0, stream>>>(dst, cnt, pos);
        k_scan1<<<SCAN_NBLK, SCAN_BS, 0, stream>>>(cnt, ends, bsum);
        k_scan2<<<1, 256, 0, stream>>>(bsum);
        k_scan3<<<SCAN_NBLK, SCAN_BS, 0, stream>>>(ends, bsum);
        k_fill2<<<ge, 256, 0, stream>>>(src, dst, pos, ends, csr);
        k_agg<<<(N_NODES + 3) / 4, 256, 0, stream>>>(x, csr, ends, out);
    } else if (ws_size >= need_old) {
        int* cnt    = (int*)d_ws;
        int* ends   = cnt + N_NODES;
        int* cursor = ends + N_NODES;
        int* bsum   = cursor + N_NODES;
        int* csr    = bsum + 512;

        k_zero<<<(N_NODES + 255) / 256, 256, 0, stream>>>(cnt, N_NODES);
        k_zero<<<(N_NODES + 255) / 256, 256, 0, stream>>>(cursor, N_NODES);
        k_hist<<<ge, 256, 0, stream>>>(dst, cnt);
        k_scan1<<<SCAN_NBLK, SCAN_BS, 0, stream>>>(cnt, ends, bsum);
        k_scan2<<<1, 256, 0, stream>>>(bsum);
        k_scan3<<<SCAN_NBLK, SCAN_BS, 0, stream>>>(ends, bsum);
        k_fill<<<ge, 256, 0, stream>>>(src, dst, ends, cursor, csr);
        k_agg<<<(N_NODES + 3) / 4, 256, 0, stream>>>(x, csr, ends, out);
    } else {
        int n4 = N_NODES * D / 4;
        k_init<<<(n4 + 255) / 256, 256, 0, stream>>>((const float4*)x, (float4*)out, n4);
        long long total = (long long)N_EDGES * 16;
        k_scatter<<<(int)((total + 255) / 256), 256, 0, stream>>>(
            (const float4*)x, src, dst, out);
    }

    k_mlp<<<(N_NODES + 31) / 32, 256, 0, stream>>>(out, W1, b1, W2, b2);
}

// Round 5
// 320.418 us; speedup vs baseline: 4.9468x; 1.0423x over previous
//
#include <hip/hip_runtime.h>

#define N_NODES 100000
#define N_EDGES 1600000
#define D 64
#define H 128
#define SCAN_BS 512
#define SCAN_NBLK ((N_NODES + SCAN_BS - 1) / SCAN_BS)   // 196

#define MLP_BS   512
#define MLP_GRID 256
#define TILE_N   64
#define NT ((N_NODES + TILE_N - 1) / TILE_N)            // 1563

// ===========================================================================
// utility
// ===========================================================================
__global__ __launch_bounds__(256) void k_zero(int* __restrict__ p, int n) {
    int i = blockIdx.x * 256 + threadIdx.x;
    if (i < n) p[i] = 0;
}

// ===========================================================================
// hist + per-edge position: pos[e] = old count of dst[e].
// ===========================================================================
__global__ __launch_bounds__(256) void k_histpos(const int* __restrict__ dst,
                                                 int* __restrict__ cnt,
                                                 int* __restrict__ pos) {
    int e = blockIdx.x * 256 + threadIdx.x;
    if (e < N_EDGES) pos[e] = atomicAdd(&cnt[dst[e]], 1);
}

__global__ __launch_bounds__(256) void k_hist(const int* __restrict__ dst,
                                              int* __restrict__ cnt) {
    int e = blockIdx.x * 256 + threadIdx.x;
    if (e < N_EDGES) atomicAdd(&cnt[dst[e]], 1);
}

// ===========================================================================
// inclusive scan of cnt -> ends (3 phases)
// ===========================================================================
__global__ __launch_bounds__(SCAN_BS) void k_scan1(const int* __restrict__ cnt,
                                                   int* __restrict__ ends,
                                                   int* __restrict__ bsum) {
    __shared__ int s[SCAN_BS];
    int t = threadIdx.x, b = blockIdx.x;
    int id = b * SCAN_BS + t;
    s[t] = (id < N_NODES) ? cnt[id] : 0;
    __syncthreads();
    for (int off = 1; off < SCAN_BS; off <<= 1) {
        int u = (t >= off) ? s[t - off] : 0;
        __syncthreads();
        s[t] += u;
        __syncthreads();
    }
    if (id < N_NODES) ends[id] = s[t];
    if (t == SCAN_BS - 1) bsum[b] = s[t];
}

__global__ __launch_bounds__(256) void k_scan2(int* __restrict__ bsum) {
    __shared__ int s[256];
    int t = threadIdx.x;
    s[t] = (t < SCAN_NBLK) ? bsum[t] : 0;
    __syncthreads();
    for (int off = 1; off < 256; off <<= 1) {
        int u = (t >= off) ? s[t - off] : 0;
        __syncthreads();
        s[t] += u;
        __syncthreads();
    }
    if (t < SCAN_NBLK) bsum[t] = s[t];
}

__global__ __launch_bounds__(SCAN_BS) void k_scan3(int* __restrict__ ends,
                                                   const int* __restrict__ bsum) {
    int t = threadIdx.x, b = blockIdx.x;
    int id = b * SCAN_BS + t;
    if (b > 0 && id < N_NODES) ends[id] += bsum[b - 1];
}

// ===========================================================================
// atomic-free CSR fill
// ===========================================================================
__global__ __launch_bounds__(256) void k_fill2(const int* __restrict__ src,
                                               const int* __restrict__ dst,
                                               const int* __restrict__ pos,
                                               const int* __restrict__ ends,
                                               int* __restrict__ csr) {
    int e = blockIdx.x * 256 + threadIdx.x;
    if (e >= N_EDGES) return;
    int d = dst[e];
    int start = (d > 0) ? ends[d - 1] : 0;
    csr[start + pos[e]] = src[e];
}

__global__ __launch_bounds__(256) void k_fill(const int* __restrict__ src,
                                              const int* __restrict__ dst,
                                              const int* __restrict__ ends,
                                              int* __restrict__ cursor,
                                              int* __restrict__ csr) {
    int e = blockIdx.x * 256 + threadIdx.x;
    if (e >= N_EDGES) return;
    int d = dst[e];
    int p = atomicAdd(&cursor[d], 1);
    int start = (d > 0) ? ends[d - 1] : 0;
    csr[start + p] = src[e];
}

// ===========================================================================
// Atomic-free aggregation: one 64-lane wave per node, lane = feature.
// ===========================================================================
__global__ __launch_bounds__(256) void k_agg(const float* __restrict__ x,
                                             const int* __restrict__ csr,
                                             const int* __restrict__ ends,
                                             float* __restrict__ out) {
    int node = blockIdx.x * 4 + (threadIdx.x >> 6);
    if (node >= N_NODES) return;
    int f = threadIdx.x & 63;
    int start = (node > 0) ? ends[node - 1] : 0;
    int end = ends[node];
    float a0 = x[(size_t)node * D + f], a1 = 0.f, a2 = 0.f, a3 = 0.f;
    int e = start;
    for (; e + 4 <= end; e += 4) {
        int s0 = csr[e], s1 = csr[e + 1], s2 = csr[e + 2], s3 = csr[e + 3];
        a0 += x[(size_t)s0 * D + f];
        a1 += x[(size_t)s1 * D + f];
        a2 += x[(size_t)s2 * D + f];
        a3 += x[(size_t)s3 * D + f];
    }
    for (; e < end; e++) a0 += x[(size_t)csr[e] * D + f];
    out[(size_t)node * D + f] = (a0 + a1) + (a2 + a3);
}

// ===========================================================================
// last-resort fallback: atomic scatter (R2-proven)
// ===========================================================================
__global__ __launch_bounds__(256) void k_init(const float4* __restrict__ x4,
                                              float4* __restrict__ agg4, int n4) {
    int i = blockIdx.x * 256 + threadIdx.x;
    if (i < n4) agg4[i] = x4[i];
}

__global__ __launch_bounds__(256) void k_scatter(const float4* __restrict__ x4,
                                                 const int* __restrict__ src,
                                                 const int* __restrict__ dst,
                                                 float* __restrict__ agg) {
    int gid = blockIdx.x * 256 + threadIdx.x;
    int e = gid >> 4;
    if (e >= N_EDGES) return;
    int c = gid & 15;
    float4 v = x4[src[e] * 16 + c];
    float* p = agg + (size_t)dst[e] * D + c * 4;
    atomicAdd(p + 0, v.x);
    atomicAdd(p + 1, v.y);
    atomicAdd(p + 2, v.z);
    atomicAdd(p + 3, v.w);
}

// ===========================================================================
// Persistent-weight fused MLP. Grid = 256 blocks (1/CU at 113 KB LDS),
// 512 threads. W1+W2 packed into LDS ONCE per block, then loop over tiles
// of 64 nodes (NT=1563 tiles, ~6 per block). Next tile's activations are
// prefetched into registers during stage-2 compute.
// group g (of 16) handles tile-local nodes {g, g+16, g+32, g+48}.
// Weight reads: ds_read_b128/b64 lane-strided (conflict-free / free 2-way);
// activation reads: b128 broadcast.
// ===========================================================================
#define FMA4(acc, xs, w) { acc.x += (xs)*w.x; acc.y += (xs)*w.y; acc.z += (xs)*w.z; acc.w += (xs)*w.w; }
#define FMA2(o, hs, w)   { o.x  += (hs)*w.x;  o.y  += (hs)*w.y; }

__global__ __launch_bounds__(MLP_BS) void k_mlp_pw(float* __restrict__ io,
                                                   const float* __restrict__ W1,
                                                   const float* __restrict__ b1,
                                                   const float* __restrict__ W2,
                                                   const float* __restrict__ b2) {
    __shared__ float sW1[D * H];        // 32 KB packed
    __shared__ float sW2[H * D];        // 32 KB packed
    __shared__ float sb1[H];
    __shared__ float sb2[D];
    __shared__ float sx[TILE_N][D];     // 16 KB
    __shared__ float sh[TILE_N][H];     // 32 KB

    int t = threadIdx.x;

    // pack weights once: sW1[(i*32+l)*4+k] = W1[i*H+l+32k]; flat p = i*128+l*4+k
    for (int p = t; p < D * H; p += MLP_BS) {
        int k = p & 3, l = (p >> 2) & 31, i = p >> 7;
        sW1[p] = W1[i * H + l + 32 * k];
    }
    // sW2[(j*32+l)*2+m] = W2[j*D+l+32m]; flat p = j*64+l*2+m
    for (int p = t; p < H * D; p += MLP_BS) {
        int m = p & 1, l = (p >> 1) & 31, j = p >> 6;
        sW2[p] = W2[j * D + l + 32 * m];
    }
    if (t < H) sb1[t] = b1[t];
    if (t >= H && t < H + D) sb2[t - H] = b2[t - H];

    int g = t >> 5, lane = t & 31;
    const float4* io4 = (const float4*)io;

    // prologue: load first tile's activations into sx
    int tt = blockIdx.x;
    if (tt < NT) {
#pragma unroll
        for (int q = 0; q < 2; q++) {
            int p = t + q * MLP_BS;                    // 0..1023 float4s
            int node = tt * TILE_N + (p >> 4);
            float4 v = make_float4(0.f, 0.f, 0.f, 0.f);
            if (node < N_NODES) v = io4[(size_t)tt * 1024 + p];
            ((float4*)sx)[p] = v;
        }
    }

    for (; tt < NT; tt += MLP_GRID) {
        __syncthreads();   // sx ready; previous tile's sh reads done

        // ---- stage 1: h = relu(x @ W1 + b1); 4 nodes x 4 outputs ----
        float4 acc0 = make_float4(sb1[lane], sb1[lane + 32], sb1[lane + 64], sb1[lane + 96]);
        float4 acc1 = acc0, acc2 = acc0, acc3 = acc0;
        for (int i = 0; i < D; i += 4) {
            float4 x0 = *(const float4*)&sx[g][i];
            float4 x1 = *(const float4*)&sx[g + 16][i];
            float4 x2 = *(const float4*)&sx[g + 32][i];
            float4 x3 = *(const float4*)&sx[g + 48][i];
            float4 w;
            w = *(const float4*)&sW1[((i + 0) * 32 + lane) * 4];
            FMA4(acc0, x0.x, w) FMA4(acc1, x1.x, w) FMA4(acc2, x2.x, w) FMA4(acc3, x3.x, w)
            w = *(const float4*)&sW1[((i + 1) * 32 + lane) * 4];
            FMA4(acc0, x0.y, w) FMA4(acc1, x1.y, w) FMA4(acc2, x2.y, w) FMA4(acc3, x3.y, w)
            w = *(const float4*)&sW1[((i + 2) * 32 + lane) * 4];
            FMA4(acc0, x0.z, w) FMA4(acc1, x1.z, w) FMA4(acc2, x2.z, w) FMA4(acc3, x3.z, w)
            w = *(const float4*)&sW1[((i + 3) * 32 + lane) * 4];
            FMA4(acc0, x0.w, w) FMA4(acc1, x1.w, w) FMA4(acc2, x2.w, w) FMA4(acc3, x3.w, w)
        }
        sh[g][lane]           = fmaxf(acc0.x, 0.f);
        sh[g][lane + 32]      = fmaxf(acc0.y, 0.f);
        sh[g][lane + 64]      = fmaxf(acc0.z, 0.f);
        sh[g][lane + 96]      = fmaxf(acc0.w, 0.f);
        sh[g + 16][lane]      = fmaxf(acc1.x, 0.f);
        sh[g + 16][lane + 32] = fmaxf(acc1.y, 0.f);
        sh[g + 16][lane + 64] = fmaxf(acc1.z, 0.f);
        sh[g + 16][lane + 96] = fmaxf(acc1.w, 0.f);
        sh[g + 32][lane]      = fmaxf(acc2.x, 0.f);
        sh[g + 32][lane + 32] = fmaxf(acc2.y, 0.f);
        sh[g + 32][lane + 64] = fmaxf(acc2.z, 0.f);
        sh[g + 32][lane + 96] = fmaxf(acc2.w, 0.f);
        sh[g + 48][lane]      = fmaxf(acc3.x, 0.f);
        sh[g + 48][lane + 32] = fmaxf(acc3.y, 0.f);
        sh[g + 48][lane + 64] = fmaxf(acc3.z, 0.f);
        sh[g + 48][lane + 96] = fmaxf(acc3.w, 0.f);
        __syncthreads();   // sh ready; sx free to overwrite

        // prefetch next tile's activations into registers (hide behind stage 2)
        int nt = tt + MLP_GRID;
        bool hn = (nt < NT);
        float4 r0 = make_float4(0.f, 0.f, 0.f, 0.f), r1 = r0;
        if (hn) {
            int p0 = t, p1 = t + MLP_BS;
            int n0 = nt * TILE_N + (p0 >> 4);
            int n1 = nt * TILE_N + (p1 >> 4);
            if (n0 < N_NODES) r0 = io4[(size_t)nt * 1024 + p0];
            if (n1 < N_NODES) r1 = io4[(size_t)nt * 1024 + p1];
        }

        // ---- stage 2: out = h @ W2 + b2; 4 nodes x 2 outputs ----
        float2 o0 = make_float2(sb2[lane], sb2[lane + 32]);
        float2 o1 = o0, o2 = o0, o3 = o0;
        for (int j = 0; j < H; j += 4) {
            float4 h0 = *(const float4*)&sh[g][j];
            float4 h1 = *(const float4*)&sh[g + 16][j];
            float4 h2 = *(const float4*)&sh[g + 32][j];
            float4 h3 = *(const float4*)&sh[g + 48][j];
            float2 w;
            w = *(const float2*)&sW2[((j + 0) * 32 + lane) * 2];
            FMA2(o0, h0.x, w) FMA2(o1, h1.x, w) FMA2(o2, h2.x, w) FMA2(o3, h3.x, w)
            w = *(const float2*)&sW2[((j + 1) * 32 + lane) * 2];
            FMA2(o0, h0.y, w) FMA2(o1, h1.y, w) FMA2(o2, h2.y, w) FMA2(o3, h3.y, w)
            w = *(const float2*)&sW2[((j + 2) * 32 + lane) * 2];
            FMA2(o0, h0.z, w) FMA2(o1, h1.z, w) FMA2(o2, h2.z, w) FMA2(o3, h3.z, w)
            w = *(const float2*)&sW2[((j + 3) * 32 + lane) * 2];
            FMA2(o0, h0.w, w) FMA2(o1, h1.w, w) FMA2(o2, h2.w, w) FMA2(o3, h3.w, w)
        }
        int base = tt * TILE_N;
        int n0 = base + g;
        if (n0 < N_NODES)      { io[(size_t)n0 * D + lane] = o0.x; io[(size_t)n0 * D + lane + 32] = o0.y; }
        int n1 = base + g + 16;
        if (n1 < N_NODES)      { io[(size_t)n1 * D + lane] = o1.x; io[(size_t)n1 * D + lane + 32] = o1.y; }
        int n2 = base + g + 32;
        if (n2 < N_NODES)      { io[(size_t)n2 * D + lane] = o2.x; io[(size_t)n2 * D + lane + 32] = o2.y; }
        int n3 = base + g + 48;
        if (n3 < N_NODES)      { io[(size_t)n3 * D + lane] = o3.x; io[(size_t)n3 * D + lane + 32] = o3.y; }

        // commit prefetched activations to sx (vmcnt wait lands here, after FMAs)
        if (hn) {
            ((float4*)sx)[t]          = r0;
            ((float4*)sx)[t + MLP_BS] = r1;
        }
    }
}

// ===========================================================================
extern "C" void kernel_launch(void* const* d_in, const int* in_sizes, int n_in,
                              void* d_out, int out_size, void* d_ws, size_t ws_size,
                              hipStream_t stream) {
    const float* x  = (const float*)d_in[0];
    const int* eidx = (const int*)d_in[1];   // [2, N_EDGES] int32 per harness
    const float* W1 = (const float*)d_in[2];
    const float* b1 = (const float*)d_in[3];
    const float* W2 = (const float*)d_in[4];
    const float* b2 = (const float*)d_in[5];
    float* out      = (float*)d_out;         // agg buffer, then final output

    const int* src = eidx;
    const int* dst = eidx + N_EDGES;

    size_t need_new = (size_t)(2 * N_NODES + 512 + 2 * N_EDGES) * sizeof(int);
    size_t need_old = (size_t)(3 * N_NODES + 512 + N_EDGES) * sizeof(int);

    int ge = (N_EDGES + 255) / 256;

    if (ws_size >= need_new) {
        int* cnt  = (int*)d_ws;
        int* ends = cnt + N_NODES;
        int* bsum = ends + N_NODES;
        int* pos  = bsum + 512;
        int* csr  = pos + N_EDGES;

        k_zero<<<(N_NODES + 255) / 256, 256, 0, stream>>>(cnt, N_NODES);
        k_histpos<<<ge, 256, 0, stream>>>(dst, cnt, pos);
        k_scan1<<<SCAN_NBLK, SCAN_BS, 0, stream>>>(cnt, ends, bsum);
        k_scan2<<<1, 256, 0, stream>>>(bsum);
        k_scan3<<<SCAN_NBLK, SCAN_BS, 0, stream>>>(ends, bsum);
        k_fill2<<<ge, 256, 0, stream>>>(src, dst, pos, ends, csr);
        k_agg<<<(N_NODES + 3) / 4, 256, 0, stream>>>(x, csr, ends, out);
    } else if (ws_size >= need_old) {
        int* cnt    = (int*)d_ws;
        int* ends   = cnt + N_NODES;
        int* cursor = ends + N_NODES;
        int* bsum   = cursor + N_NODES;
        int* csr    = bsum + 512;

        k_zero<<<(N_NODES + 255) / 256, 256, 0, stream>>>(cnt, N_NODES);
        k_zero<<<(N_NODES + 255) / 256, 256, 0, stream>>>(cursor, N_NODES);
        k_hist<<<ge, 256, 0, stream>>>(dst, cnt);
        k_scan1<<<SCAN_NBLK, SCAN_BS, 0, stream>>>(cnt, ends, bsum);
        k_scan2<<<1, 256, 0, stream>>>(bsum);
        k_scan3<<<SCAN_NBLK, SCAN_BS, 0, stream>>>(ends, bsum);
        k_fill<<<ge, 256, 0, stream>>>(src, dst, ends, cursor, csr);
        k_agg<<<(N_NODES + 3) / 4, 256, 0, stream>>>(x, csr, ends, out);
    } else {
        int n4 = N_NODES * D / 4;
        k_init<<<(n4 + 255) / 256, 256, 0, stream>>>((const float4*)x, (float4*)out, n4);
        long long total = (long long)N_EDGES * 16;
        k_scatter<<<(int)((total + 255) / 256), 256, 0, stream>>>(
            (const float4*)x, src, dst, out);
    }

    k_mlp_pw<<<MLP_GRID, MLP_BS, 0, stream>>>(out, W1, b1, W2, b2);
}

// Round 6
// 270.613 us; speedup vs baseline: 5.8572x; 1.1840x over previous
//
#include <hip/hip_runtime.h>

#define N_NODES 100000
#define N_EDGES 1600000
#define D 64
#define H 128
#define SCAN_BS 512
#define SCAN_NBLK ((N_NODES + SCAN_BS - 1) / SCAN_BS)   // 196

#define MFMA_GRID 512        // 2 blocks/CU
#define SH_STRIDE 132        // h-buffer row stride (words): 16B-aligned, 2-way banks

typedef __attribute__((ext_vector_type(8))) short short8;   // 8 x bf16 (4 VGPRs)
typedef __attribute__((ext_vector_type(4))) float floatx4;  // MFMA acc

__device__ __forceinline__ unsigned short f2bf(float f) {
    unsigned u = __builtin_bit_cast(unsigned, f);
    u += 0x7FFFu + ((u >> 16) & 1u);          // round-to-nearest-even
    return (unsigned short)(u >> 16);
}

// ===========================================================================
// utility
// ===========================================================================
__global__ __launch_bounds__(256) void k_zero(int* __restrict__ p, int n) {
    int i = blockIdx.x * 256 + threadIdx.x;
    if (i < n) p[i] = 0;
}

// ===========================================================================
// hist + per-edge position: pos[e] = old count of dst[e].
// ===========================================================================
__global__ __launch_bounds__(256) void k_histpos(const int* __restrict__ dst,
                                                 int* __restrict__ cnt,
                                                 int* __restrict__ pos) {
    int e = blockIdx.x * 256 + threadIdx.x;
    if (e < N_EDGES) pos[e] = atomicAdd(&cnt[dst[e]], 1);
}

__global__ __launch_bounds__(256) void k_hist(const int* __restrict__ dst,
                                              int* __restrict__ cnt) {
    int e = blockIdx.x * 256 + threadIdx.x;
    if (e < N_EDGES) atomicAdd(&cnt[dst[e]], 1);
}

// ===========================================================================
// inclusive scan of cnt -> ends (3 phases)
// ===========================================================================
__global__ __launch_bounds__(SCAN_BS) void k_scan1(const int* __restrict__ cnt,
                                                   int* __restrict__ ends,
                                                   int* __restrict__ bsum) {
    __shared__ int s[SCAN_BS];
    int t = threadIdx.x, b = blockIdx.x;
    int id = b * SCAN_BS + t;
    s[t] = (id < N_NODES) ? cnt[id] : 0;
    __syncthreads();
    for (int off = 1; off < SCAN_BS; off <<= 1) {
        int u = (t >= off) ? s[t - off] : 0;
        __syncthreads();
        s[t] += u;
        __syncthreads();
    }
    if (id < N_NODES) ends[id] = s[t];
    if (t == SCAN_BS - 1) bsum[b] = s[t];
}

__global__ __launch_bounds__(256) void k_scan2(int* __restrict__ bsum) {
    __shared__ int s[256];
    int t = threadIdx.x;
    s[t] = (t < SCAN_NBLK) ? bsum[t] : 0;
    __syncthreads();
    for (int off = 1; off < 256; off <<= 1) {
        int u = (t >= off) ? s[t - off] : 0;
        __syncthreads();
        s[t] += u;
        __syncthreads();
    }
    if (t < SCAN_NBLK) bsum[t] = s[t];
}

__global__ __launch_bounds__(SCAN_BS) void k_scan3(int* __restrict__ ends,
                                                   const int* __restrict__ bsum) {
    int t = threadIdx.x, b = blockIdx.x;
    int id = b * SCAN_BS + t;
    if (b > 0 && id < N_NODES) ends[id] += bsum[b - 1];
}

// ===========================================================================
// atomic-free CSR fill
// ===========================================================================
__global__ __launch_bounds__(256) void k_fill2(const int* __restrict__ src,
                                               const int* __restrict__ dst,
                                               const int* __restrict__ pos,
                                               const int* __restrict__ ends,
                                               int* __restrict__ csr) {
    int e = blockIdx.x * 256 + threadIdx.x;
    if (e >= N_EDGES) return;
    int d = dst[e];
    int start = (d > 0) ? ends[d - 1] : 0;
    csr[start + pos[e]] = src[e];
}

__global__ __launch_bounds__(256) void k_fill(const int* __restrict__ src,
                                              const int* __restrict__ dst,
                                              const int* __restrict__ ends,
                                              int* __restrict__ cursor,
                                              int* __restrict__ csr) {
    int e = blockIdx.x * 256 + threadIdx.x;
    if (e >= N_EDGES) return;
    int d = dst[e];
    int p = atomicAdd(&cursor[d], 1);
    int start = (d > 0) ? ends[d - 1] : 0;
    csr[start + p] = src[e];
}

// ===========================================================================
// Atomic-free aggregation: one 64-lane wave per node, lane = feature.
// ===========================================================================
__global__ __launch_bounds__(256) void k_agg(const float* __restrict__ x,
                                             const int* __restrict__ csr,
                                             const int* __restrict__ ends,
                                             float* __restrict__ out) {
    int node = blockIdx.x * 4 + (threadIdx.x >> 6);
    if (node >= N_NODES) return;
    int f = threadIdx.x & 63;
    int start = (node > 0) ? ends[node - 1] : 0;
    int end = ends[node];
    float a0 = x[(size_t)node * D + f], a1 = 0.f, a2 = 0.f, a3 = 0.f;
    int e = start;
    for (; e + 4 <= end; e += 4) {
        int s0 = csr[e], s1 = csr[e + 1], s2 = csr[e + 2], s3 = csr[e + 3];
        a0 += x[(size_t)s0 * D + f];
        a1 += x[(size_t)s1 * D + f];
        a2 += x[(size_t)s2 * D + f];
        a3 += x[(size_t)s3 * D + f];
    }
    for (; e < end; e++) a0 += x[(size_t)csr[e] * D + f];
    out[(size_t)node * D + f] = (a0 + a1) + (a2 + a3);
}

// ===========================================================================
// last-resort fallback: atomic scatter (R2-proven)
// ===========================================================================
__global__ __launch_bounds__(256) void k_init(const float4* __restrict__ x4,
                                              float4* __restrict__ agg4, int n4) {
    int i = blockIdx.x * 256 + threadIdx.x;
    if (i < n4) agg4[i] = x4[i];
}

__global__ __launch_bounds__(256) void k_scatter(const float4* __restrict__ x4,
                                                 const int* __restrict__ src,
                                                 const int* __restrict__ dst,
                                                 float* __restrict__ agg) {
    int gid = blockIdx.x * 256 + threadIdx.x;
    int e = gid >> 4;
    if (e >= N_EDGES) return;
    int c = gid & 15;
    float4 v = x4[src[e] * 16 + c];
    float* p = agg + (size_t)dst[e] * D + c * 4;
    atomicAdd(p + 0, v.x);
    atomicAdd(p + 1, v.y);
    atomicAdd(p + 2, v.z);
    atomicAdd(p + 3, v.w);
}

// ===========================================================================
// MFMA bf16 fused MLP, in-place on d_out.
// One wave per 16-node tile; mfma_f32_16x16x32_bf16.
//   A-frag: lane holds x[m = lane&15][k = (lane>>4)*8 + j], j=0..7  -> the 8
//           floats are CONTIGUOUS in the activation row: direct global float4
//           loads, cvt to bf16 in-reg.
//   B-frag: lane holds W[k = (lane>>4)*8 + j][n = lane&15] -> packed once per
//           block into LDS (bf16) so each frag is one ds_read_b128.
//   C/D:    lane holds [row = (lane>>4)*4 + r][col = lane&15].
// h round-trips through a per-wave LDS buffer (fp32, row stride 132 words:
// 16B-aligned for b128, 2-way bank pattern = free) to convert C-layout ->
// A-layout between the two GEMMs. Bias folded into the C operand; relu at
// the C->LDS step. 100000 % 16 == 0: no tail handling.
// LDS: 16K (W1b) + 16K (W2b) + 33K (sh) + biases ~= 67 KB -> 2 blocks/CU.
// ===========================================================================
__global__ __launch_bounds__(256) void k_mlp_mfma(float* __restrict__ io,
                                                  const float* __restrict__ W1,
                                                  const float* __restrict__ b1,
                                                  const float* __restrict__ W2,
                                                  const float* __restrict__ b2) {
    __shared__ unsigned short sW1b[8192];       // 16 KB: frag f=(kt*8+nt), idx (f*64+l)*8+j
    __shared__ unsigned short sW2b[8192];       // 16 KB: frag f=(kt*4+nt)
    __shared__ float sh[4][16 * SH_STRIDE];     // 33 KB: per-wave h buffer
    __shared__ float sb1[H];
    __shared__ float sb2[D];

    int t = threadIdx.x;

    // pack W1 [64][128] -> B-frag layout, bf16
    for (int q = t; q < 8192; q += 256) {
        int j = q & 7, l = (q >> 3) & 63, f = q >> 9;
        int nt = f & 7, kt = f >> 3;
        int k = kt * 32 + ((l >> 4) << 3) + j;
        int n = nt * 16 + (l & 15);
        sW1b[q] = f2bf(W1[k * H + n]);
    }
    // pack W2 [128][64]
    for (int q = t; q < 8192; q += 256) {
        int j = q & 7, l = (q >> 3) & 63, f = q >> 9;
        int nt = f & 3, kt = f >> 2;
        int k = kt * 32 + ((l >> 4) << 3) + j;
        int n = nt * 16 + (l & 15);
        sW2b[q] = f2bf(W2[k * D + n]);
    }
    if (t < H) sb1[t] = b1[t];
    if (t >= H && t < H + D) sb2[t - H] = b2[t - H];
    __syncthreads();

    int w = t >> 6, l = t & 63;
    int m = l & 15, q4 = l >> 4;
    float* shw = sh[w];

    const int NT16 = N_NODES / 16;              // 6250 tiles, exact
    const int WAVES = MFMA_GRID * 4;            // 2048
    const int ITERS = (NT16 + WAVES - 1) / WAVES;

    for (int it = 0; it < ITERS; ++it) {
        int tl = it * WAVES + blockIdx.x * 4 + w;
        bool valid = tl < NT16;
        int nbase = tl * 16;

        if (valid) {
            // ---- A-frags from global (activations), cvt to bf16 ----
            const float* xr = io + (size_t)(nbase + m) * D + q4 * 8;
            float4 a0 = *(const float4*)(xr);
            float4 a1 = *(const float4*)(xr + 4);
            float4 c0 = *(const float4*)(xr + 32);
            float4 c1 = *(const float4*)(xr + 36);
            short8 A0, A1;
            A0[0] = f2bf(a0.x); A0[1] = f2bf(a0.y); A0[2] = f2bf(a0.z); A0[3] = f2bf(a0.w);
            A0[4] = f2bf(a1.x); A0[5] = f2bf(a1.y); A0[6] = f2bf(a1.z); A0[7] = f2bf(a1.w);
            A1[0] = f2bf(c0.x); A1[1] = f2bf(c0.y); A1[2] = f2bf(c0.z); A1[3] = f2bf(c0.w);
            A1[4] = f2bf(c1.x); A1[5] = f2bf(c1.y); A1[6] = f2bf(c1.z); A1[7] = f2bf(c1.w);

            // ---- stage 1: h = relu(x @ W1 + b1); 8 N-tiles x 2 K-tiles ----
#pragma unroll
            for (int nt = 0; nt < 8; nt++) {
                float bv = sb1[nt * 16 + m];
                floatx4 acc = {bv, bv, bv, bv};
                short8 B0 = *(const short8*)&sW1b[(0 * 8 + nt) * 512 + l * 8];
                short8 B1 = *(const short8*)&sW1b[(1 * 8 + nt) * 512 + l * 8];
                acc = __builtin_amdgcn_mfma_f32_16x16x32_bf16(A0, B0, acc, 0, 0, 0);
                acc = __builtin_amdgcn_mfma_f32_16x16x32_bf16(A1, B1, acc, 0, 0, 0);
#pragma unroll
                for (int r = 0; r < 4; r++)
                    shw[(q4 * 4 + r) * SH_STRIDE + nt * 16 + m] = fmaxf(acc[r], 0.f);
            }
        }
        __syncthreads();   // sh C-layout writes -> A-layout reads (wave-local, barrier for safety)

        if (valid) {
            // ---- h from LDS in A-layout, cvt to bf16 ----
            short8 Ah[4];
#pragma unroll
            for (int kt = 0; kt < 4; kt++) {
                const float* hr = &shw[m * SH_STRIDE + kt * 32 + q4 * 8];
                float4 h0 = *(const float4*)(hr);
                float4 h1 = *(const float4*)(hr + 4);
                Ah[kt][0] = f2bf(h0.x); Ah[kt][1] = f2bf(h0.y);
                Ah[kt][2] = f2bf(h0.z); Ah[kt][3] = f2bf(h0.w);
                Ah[kt][4] = f2bf(h1.x); Ah[kt][5] = f2bf(h1.y);
                Ah[kt][6] = f2bf(h1.z); Ah[kt][7] = f2bf(h1.w);
            }
            // ---- stage 2: out = h @ W2 + b2; 4 N-tiles x 4 K-tiles ----
#pragma unroll
            for (int nt = 0; nt < 4; nt++) {
                float bv = sb2[nt * 16 + m];
                floatx4 acc = {bv, bv, bv, bv};
#pragma unroll
                for (int kt = 0; kt < 4; kt++) {
                    short8 B = *(const short8*)&sW2b[(kt * 4 + nt) * 512 + l * 8];
                    acc = __builtin_amdgcn_mfma_f32_16x16x32_bf16(Ah[kt], B, acc, 0, 0, 0);
                }
#pragma unroll
                for (int r = 0; r < 4; r++)
                    io[(size_t)(nbase + q4 * 4 + r) * D + nt * 16 + m] = acc[r];
            }
        }
        __syncthreads();   // WAR: next iter's sh writes vs this iter's reads
    }
}

// ===========================================================================
extern "C" void kernel_launch(void* const* d_in, const int* in_sizes, int n_in,
                              void* d_out, int out_size, void* d_ws, size_t ws_size,
                              hipStream_t stream) {
    const float* x  = (const float*)d_in[0];
    const int* eidx = (const int*)d_in[1];   // [2, N_EDGES] int32 per harness
    const float* W1 = (const float*)d_in[2];
    const float* b1 = (const float*)d_in[3];
    const float* W2 = (const float*)d_in[4];
    const float* b2 = (const float*)d_in[5];
    float* out      = (float*)d_out;         // agg buffer, then final output

    const int* src = eidx;
    const int* dst = eidx + N_EDGES;

    size_t need_new = (size_t)(2 * N_NODES + 512 + 2 * N_EDGES) * sizeof(int);
    size_t need_old = (size_t)(3 * N_NODES + 512 + N_EDGES) * sizeof(int);

    int ge = (N_EDGES + 255) / 256;

    if (ws_size >= need_new) {
        int* cnt  = (int*)d_ws;
        int* ends = cnt + N_NODES;
        int* bsum = ends + N_NODES;
        int* pos  = bsum + 512;
        int* csr  = pos + N_EDGES;

        k_zero<<<(N_NODES + 255) / 256, 256, 0, stream>>>(cnt, N_NODES);
        k_histpos<<<ge, 256, 0, stream>>>(dst, cnt, pos);
        k_scan1<<<SCAN_NBLK, SCAN_BS, 0, stream>>>(cnt, ends, bsum);
        k_scan2<<<1, 256, 0, stream>>>(bsum);
        k_scan3<<<SCAN_NBLK, SCAN_BS, 0, stream>>>(ends, bsum);
        k_fill2<<<ge, 256, 0, stream>>>(src, dst, pos, ends, csr);
        k_agg<<<(N_NODES + 3) / 4, 256, 0, stream>>>(x, csr, ends, out);
    } else if (ws_size >= need_old) {
        int* cnt    = (int*)d_ws;
        int* ends   = cnt + N_NODES;
        int* cursor = ends + N_NODES;
        int* bsum   = cursor + N_NODES;
        int* csr    = bsum + 512;

        k_zero<<<(N_NODES + 255) / 256, 256, 0, stream>>>(cnt, N_NODES);
        k_zero<<<(N_NODES + 255) / 256, 256, 0, stream>>>(cursor, N_NODES);
        k_hist<<<ge, 256, 0, stream>>>(dst, cnt);
        k_scan1<<<SCAN_NBLK, SCAN_BS, 0, stream>>>(cnt, ends, bsum);
        k_scan2<<<1, 256, 0, stream>>>(bsum);
        k_scan3<<<SCAN_NBLK, SCAN_BS, 0, stream>>>(ends, bsum);
        k_fill<<<ge, 256, 0, stream>>>(src, dst, ends, cursor, csr);
        k_agg<<<(N_NODES + 3) / 4, 256, 0, stream>>>(x, csr, ends, out);
    } else {
        int n4 = N_NODES * D / 4;
        k_init<<<(n4 + 255) / 256, 256, 0, stream>>>((const float4*)x, (float4*)out, n4);
        long long total = (long long)N_EDGES * 16;
        k_scatter<<<(int)((total + 255) / 256), 256, 0, stream>>>(
            (const float4*)x, src, dst, out);
    }

    k_mlp_mfma<<<MFMA_GRID, 256, 0, stream>>>(out, W1, b1, W2, b2);
}